// Round 1
// baseline (381.557 us; speedup 1.0000x reference)
//
#include <hip/hip_runtime.h>

#define B 2
#define T 2048
#define HID 1536
#define NH 12
#define DK 16
#define DV 128
#define BT (B * T)
#define EPS 1e-12f

typedef __attribute__((ext_vector_type(8))) short bf16x8;
typedef __attribute__((ext_vector_type(4))) short bf16x4;
typedef __attribute__((ext_vector_type(4))) float f32x4;

__device__ __forceinline__ unsigned short f2bf(float f) {
    unsigned int u = __float_as_uint(f);
    u += 0x7FFFu + ((u >> 16) & 1u);
    return (unsigned short)(u >> 16);
}

// 16x16x16 bf16 MFMA (K=16 exactly matches DK; C/D frag layout == B frag layout)
#if __has_builtin(__builtin_amdgcn_mfma_f32_16x16x16bf16_1k)
__device__ __forceinline__ f32x4 mfma16(bf16x4 a, bf16x4 b, f32x4 c) {
    return __builtin_amdgcn_mfma_f32_16x16x16bf16_1k(a, b, c, 0, 0, 0);
}
#else
__device__ __forceinline__ f32x4 mfma16(bf16x4 a, bf16x4 b, f32x4 c) {
    asm("v_mfma_f32_16x16x16_bf16 %0, %1, %2, %0" : "+v"(c) : "v"(a), "v"(b));
    return c;
}
#endif

__device__ __forceinline__ unsigned int cvt_pk_bf16(float lo, float hi) {
    unsigned int r;
    asm("v_cvt_pk_bf16_f32 %0, %1, %2" : "=v"(r) : "v"(lo), "v"(hi));
    return r;
}

// ---------------------------------------------------------------------------
// Fused fp32->bf16 for all 5 inputs. Segments in 2048-element blocks:
// hs 3072 | Wq 144 | Wk 144 | Wv 1152 | Wo 1152 = 5664 blocks.
// Wq+Wk land concatenated in wqk [384][1536].
// ---------------------------------------------------------------------------
__global__ __launch_bounds__(256) void cvt_all(const float* __restrict__ hs,
                                               const float* __restrict__ Wq,
                                               const float* __restrict__ Wk,
                                               const float* __restrict__ Wv,
                                               const float* __restrict__ Wo,
                                               unsigned short* __restrict__ hsb,
                                               unsigned short* __restrict__ wqk,
                                               unsigned short* __restrict__ wvb,
                                               unsigned short* __restrict__ wob) {
    int bx = blockIdx.x;
    const float* src;
    unsigned short* dst;
    if (bx < 3072)      { src = hs; dst = hsb; }
    else if (bx < 3216) { src = Wq; dst = wqk;          bx -= 3072; }
    else if (bx < 3360) { src = Wk; dst = wqk + 294912; bx -= 3216; }
    else if (bx < 4512) { src = Wv; dst = wvb;          bx -= 3360; }
    else                { src = Wo; dst = wob;          bx -= 4512; }
    const int i = (bx * 256 + threadIdx.x) * 8;
    float4 a = *(const float4*)(src + i);
    float4 b = *(const float4*)(src + i + 4);
    *(ushort4*)(dst + i)     = make_ushort4(f2bf(a.x), f2bf(a.y), f2bf(a.z), f2bf(a.w));
    *(ushort4*)(dst + i + 4) = make_ushort4(f2bf(b.x), f2bf(b.y), f2bf(b.z), f2bf(b.w));
}

// ---------------------------------------------------------------------------
// Generic m97-style 128x128 bf16 GEMM tile body (BK=32, global_load_lds w=16,
// 16x16x32 MFMA, 4 waves x 4x4 frags). C bf16 row-major, no store guards
// (M,N multiples of 128).
// ---------------------------------------------------------------------------
__device__ __forceinline__ void gemm_tile_bf16(const unsigned short* __restrict__ A,
                                               const unsigned short* __restrict__ Bm,
                                               unsigned short* __restrict__ C,
                                               int m0, int n0, int K, int ldc,
                                               unsigned short* As, unsigned short* Bs) {
    const int tid = threadIdx.x;
    const int wave = tid >> 6, lane = tid & 63;
    const int wm = (wave & 1) * 64, wn = (wave >> 1) * 64;
    const int fr = lane & 15;
    const int fk = (lane >> 4) * 8;

    f32x4 acc[4][4];
#pragma unroll
    for (int i = 0; i < 4; ++i)
#pragma unroll
        for (int j = 0; j < 4; ++j) acc[i][j] = (f32x4)0.f;

    const int c0 = tid, c1 = tid + 256;
    const int r0 = c0 >> 2, q0 = (c0 & 3) * 8;
    const int r1 = c1 >> 2, q1 = (c1 & 3) * 8;

    for (int k0 = 0; k0 < K; k0 += 32) {
        __builtin_amdgcn_global_load_lds(
            (const __attribute__((address_space(1))) void*)(A + (size_t)(m0 + r0) * K + k0 + q0),
            (__attribute__((address_space(3))) void*)(As + c0 * 8), 16, 0, 0);
        __builtin_amdgcn_global_load_lds(
            (const __attribute__((address_space(1))) void*)(A + (size_t)(m0 + r1) * K + k0 + q1),
            (__attribute__((address_space(3))) void*)(As + c1 * 8), 16, 0, 0);
        __builtin_amdgcn_global_load_lds(
            (const __attribute__((address_space(1))) void*)(Bm + (size_t)(n0 + r0) * K + k0 + q0),
            (__attribute__((address_space(3))) void*)(Bs + c0 * 8), 16, 0, 0);
        __builtin_amdgcn_global_load_lds(
            (const __attribute__((address_space(1))) void*)(Bm + (size_t)(n0 + r1) * K + k0 + q1),
            (__attribute__((address_space(3))) void*)(Bs + c1 * 8), 16, 0, 0);
        __syncthreads();

        bf16x8 af[4], bfr[4];
#pragma unroll
        for (int mb = 0; mb < 4; ++mb)
            af[mb] = *(const bf16x8*)(As + (wm + mb * 16 + fr) * 32 + fk);
#pragma unroll
        for (int nb = 0; nb < 4; ++nb)
            bfr[nb] = *(const bf16x8*)(Bs + (wn + nb * 16 + fr) * 32 + fk);
#pragma unroll
        for (int mb = 0; mb < 4; ++mb)
#pragma unroll
            for (int nb = 0; nb < 4; ++nb)
                acc[mb][nb] = __builtin_amdgcn_mfma_f32_16x16x32_bf16(
                    af[mb], bfr[nb], acc[mb][nb], 0, 0, 0);
        __syncthreads();
    }

    const int orow = (lane >> 4) * 4;
#pragma unroll
    for (int nb = 0; nb < 4; ++nb) {
        const int col = n0 + wn + nb * 16 + fr;
#pragma unroll
        for (int mb = 0; mb < 4; ++mb) {
            const int row = m0 + wm + mb * 16 + orow;
#pragma unroll
            for (int r = 0; r < 4; ++r)
                C[(size_t)(row + r) * ldc + col] = f2bf(acc[mb][nb][r]);
        }
    }
}

// ---------------------------------------------------------------------------
// Fused QK-proj + V^T-proj, one launch, 480 blocks:
//   bx <  96: qk[BT][384] = hsb @ wqk^T           (m-tile bx/3, n-tile bx%3)
//   bx >= 96: vt[HID][BT] = wvb @ hsb^T (V^T)      (4-wide n-supertile swizzle)
// ---------------------------------------------------------------------------
__global__ __launch_bounds__(256) void proj_qkv(const unsigned short* __restrict__ hsb,
                                                const unsigned short* __restrict__ wqk,
                                                const unsigned short* __restrict__ wvb,
                                                unsigned short* __restrict__ qkb,
                                                unsigned short* __restrict__ vtg) {
    __shared__ unsigned short As[128 * 32];
    __shared__ unsigned short Bs[128 * 32];
    const int bx = blockIdx.x;
    if (bx < 96) {
        gemm_tile_bf16(hsb, wqk, qkb, (bx / 3) * 128, (bx % 3) * 128, HID, 384, As, Bs);
    } else {
        const int vid = bx - 96;
        const int grp = vid / 48, sub = vid % 48;
        const int n_t = grp * 4 + (sub & 3), m_t = sub >> 2;
        gemm_tile_bf16(wvb, hsb, vtg, m_t * 128, n_t * 128, HID, BT, As, Bs);
    }
}

// ---------------------------------------------------------------------------
// Output projection: out[BT][HID] fp32 = ybb @ wob^T.
// ---------------------------------------------------------------------------
__global__ __launch_bounds__(256) void proj_out(const unsigned short* __restrict__ A,
                                                const unsigned short* __restrict__ Bm,
                                                float* __restrict__ C) {
    __shared__ unsigned short As[128 * 32];
    __shared__ unsigned short Bs[128 * 32];
    const int tid = threadIdx.x;
    const int m0 = blockIdx.y * 128;
    const int n0 = blockIdx.x * 128;
    const int wave = tid >> 6, lane = tid & 63;
    const int wm = (wave & 1) * 64, wn = (wave >> 1) * 64;
    const int fr = lane & 15;
    const int fk = (lane >> 4) * 8;
    const int K = HID;

    f32x4 acc[4][4];
#pragma unroll
    for (int i = 0; i < 4; ++i)
#pragma unroll
        for (int j = 0; j < 4; ++j) acc[i][j] = (f32x4)0.f;

    const int c0 = tid, c1 = tid + 256;
    const int r0 = c0 >> 2, q0 = (c0 & 3) * 8;
    const int r1 = c1 >> 2, q1 = (c1 & 3) * 8;

    for (int k0 = 0; k0 < K; k0 += 32) {
        __builtin_amdgcn_global_load_lds(
            (const __attribute__((address_space(1))) void*)(A + (size_t)(m0 + r0) * K + k0 + q0),
            (__attribute__((address_space(3))) void*)(As + c0 * 8), 16, 0, 0);
        __builtin_amdgcn_global_load_lds(
            (const __attribute__((address_space(1))) void*)(A + (size_t)(m0 + r1) * K + k0 + q1),
            (__attribute__((address_space(3))) void*)(As + c1 * 8), 16, 0, 0);
        __builtin_amdgcn_global_load_lds(
            (const __attribute__((address_space(1))) void*)(Bm + (size_t)(n0 + r0) * K + k0 + q0),
            (__attribute__((address_space(3))) void*)(Bs + c0 * 8), 16, 0, 0);
        __builtin_amdgcn_global_load_lds(
            (const __attribute__((address_space(1))) void*)(Bm + (size_t)(n0 + r1) * K + k0 + q1),
            (__attribute__((address_space(3))) void*)(Bs + c1 * 8), 16, 0, 0);
        __syncthreads();

        bf16x8 af[4], bfr[4];
#pragma unroll
        for (int mb = 0; mb < 4; ++mb)
            af[mb] = *(const bf16x8*)(As + (wm + mb * 16 + fr) * 32 + fk);
#pragma unroll
        for (int nb = 0; nb < 4; ++nb)
            bfr[nb] = *(const bf16x8*)(Bs + (wn + nb * 16 + fr) * 32 + fk);
#pragma unroll
        for (int mb = 0; mb < 4; ++mb)
#pragma unroll
            for (int nb = 0; nb < 4; ++nb)
                acc[mb][nb] = __builtin_amdgcn_mfma_f32_16x16x32_bf16(
                    af[mb], bfr[nb], acc[mb][nb], 0, 0, 0);
        __syncthreads();
    }

    const int orow = (lane >> 4) * 4;
#pragma unroll
    for (int nb = 0; nb < 4; ++nb) {
        const int col = n0 + wn + nb * 16 + fr;
#pragma unroll
        for (int mb = 0; mb < 4; ++mb) {
            const int row = m0 + wm + mb * 16 + orow;
#pragma unroll
            for (int r = 0; r < 4; ++r)
                C[(size_t)(row + r) * HID + col] = acc[mb][nb][r];
        }
    }
}

// ---------------------------------------------------------------------------
// MFMA causal Taylor linear attention — barrier-free key-partition version.
//   Wave w owns key strip j in [16w,16w+16) of every kt tile.
//   S^T(strip) = K Q^T via 16x16x16 MFMA (K=DK=16 exact, no padding).
//   16x16x16 C/D layout (row=quad*4+r, col=fr) == B layout (k=quad*4+reg,
//   n=fr), so S^T frag -> poly -> cvt_pk bf16 stays IN-LANE and feeds the
//   O-MFMA B operand directly: no LDS, no barriers in the kt loop.
//   Each wave accumulates partial O^T[128][64] (its keys only) in 128 VGPRs;
//   waves combine once at the end via ds_add_f32 into padded LDS ([128][66]
//   -> 2-way max, free). den likewise.
//   768 blocks, qt-major heavy-first; prefetch of kt+1 K/V frags as before.
// ---------------------------------------------------------------------------
__global__ __launch_bounds__(256, 2) void based_attn_mfma(const unsigned short* __restrict__ qk,
                                                          const unsigned short* __restrict__ vt,
                                                          unsigned short* __restrict__ yb) {
    const int bx = blockIdx.x;
    const int qt = (T / 64 - 1) - (bx / (NH * B));
    const int hb = bx % (NH * B);
    const int h  = hb >> 1;
    const int bi = hb & 1;
    const int tid = threadIdx.x;
    const int wave = tid >> 6, lane = tid & 63;
    const int fr = lane & 15, quad = lane >> 4;

    __shared__ float olds[128][66];   // padded: ds_add banks (8*quad+fr)%32 -> 2-way
    __shared__ float den_lds[64];

    for (int idx = tid; idx < 128 * 66; idx += 256) (&olds[0][0])[idx] = 0.f;
    if (tid < 64) den_lds[tid] = 0.f;
    __syncthreads();

    // persistent Q B-frags: B[k=quad*4+s][n=fr] = Q[qt*64+nt*16+fr][k]
    bf16x4 qf[4];
#pragma unroll
    for (int nt = 0; nt < 4; ++nt)
        qf[nt] = *(const bf16x4*)(qk + (size_t)(bi * T + qt * 64 + nt * 16 + fr) * 384
                                  + h * DK + quad * 4);

    f32x4 oacc[8][4];
#pragma unroll
    for (int mt = 0; mt < 8; ++mt)
#pragma unroll
        for (int nt = 0; nt < 4; ++nt) oacc[mt][nt] = (f32x4)0.f;
    float denp[4] = {0.f, 0.f, 0.f, 0.f};

    // K A-frag: A[m=fr][k=quad*4+s] = K[kt*64+16w+fr][k]
    const unsigned short* kbase = qk + (size_t)(bi * T + wave * 16 + fr) * 384
                                  + 192 + h * DK + quad * 4;
    // V A-frag: A[m=fr][k=quad*4+s] = V^T[h*DV+mt*16+fr][kt*64+16w+quad*4+s]
    const unsigned short* vbase = vt + (size_t)(h * DV + fr) * BT
                                  + bi * T + wave * 16 + quad * 4;

    // prologue: prefetch kt=0
    bf16x4 kf_n = *(const bf16x4*)kbase;
    bf16x4 vf_n[8];
#pragma unroll
    for (int mt = 0; mt < 8; ++mt)
        vf_n[mt] = *(const bf16x4*)(vbase + (size_t)mt * 16 * BT);

    for (int kt = 0; kt <= qt; ++kt) {
        const bf16x4 kf = kf_n;
        bf16x4 vf[8];
#pragma unroll
        for (int mt = 0; mt < 8; ++mt) vf[mt] = vf_n[mt];

        // prefetch kt+1 (clamped on last iteration; redundant but in-bounds)
        {
            const int ktn = (kt < qt) ? kt + 1 : qt;
            kf_n = *(const bf16x4*)(kbase + (size_t)ktn * 64 * 384);
#pragma unroll
            for (int mt = 0; mt < 8; ++mt)
                vf_n[mt] = *(const bf16x4*)(vbase + (size_t)mt * 16 * BT + ktn * 64);
        }

        // S^T strip: rows j = 16w+quad*4+r, cols i = nt*16+fr; poly + pack in-lane
        bf16x4 sb[4];
#pragma unroll
        for (int nt = 0; nt < 4; ++nt) {
            f32x4 sa = mfma16(kf, qf[nt], (f32x4)0.f);
            float sv[4];
#pragma unroll
            for (int r = 0; r < 4; ++r) {
                const float a = sa[r];
                sv[r] = fmaf(a, fmaf(a, 1.f / 32.f, 0.25f), 1.f);
            }
            if (kt == qt) {   // block-uniform: causal mask only on diag tile
                const int i = nt * 16 + fr;
#pragma unroll
                for (int r = 0; r < 4; ++r)
                    if (wave * 16 + quad * 4 + r > i) sv[r] = 0.f;
            }
            denp[nt] += (sv[0] + sv[1]) + (sv[2] + sv[3]);
            union { uint2 u; bf16x4 v; } pk;
            pk.u.x = cvt_pk_bf16(sv[0], sv[1]);
            pk.u.y = cvt_pk_bf16(sv[2], sv[3]);
            sb[nt] = pk.v;
        }

        // partial O^T (this wave's keys only): all 128 V rows, k-depth 16
#pragma unroll
        for (int mt = 0; mt < 8; ++mt)
#pragma unroll
            for (int nt = 0; nt < 4; ++nt)
                oacc[mt][nt] = mfma16(vf[mt], sb[nt], oacc[mt][nt]);
    }

    // den: quad-reduce (same fr), then cross-wave via LDS atomics
#pragma unroll
    for (int nt = 0; nt < 4; ++nt) {
        float v = denp[nt];
        v += __shfl_xor(v, 16);
        v += __shfl_xor(v, 32);
        if (quad == 0) atomicAdd(&den_lds[nt * 16 + fr], v);
    }

    // O: cross-wave reduce via ds_add_f32 (once per block)
#pragma unroll
    for (int mt = 0; mt < 8; ++mt)
#pragma unroll
        for (int nt = 0; nt < 4; ++nt)
#pragma unroll
            for (int r = 0; r < 4; ++r)
                atomicAdd(&olds[mt * 16 + quad * 4 + r][nt * 16 + fr], oacc[mt][nt][r]);
    __syncthreads();

    // y[i][c] = O^T[c][i] / den[i], bf16 row-major [BT][HID]
    {
        const int i = tid & 63;          // query index (lane)
        const int cb = (tid >> 6) * 32;  // wave's 32-wide c chunk
        const float rd = 1.f / (den_lds[i] + EPS);
        const size_t rowbase = (size_t)(bi * T + qt * 64 + i) * (NH * DV) + h * DV;
#pragma unroll
        for (int cc = 0; cc < 32; cc += 4) {
            ushort4 o;
            o.x = f2bf(olds[cb + cc + 0][i] * rd);
            o.y = f2bf(olds[cb + cc + 1][i] * rd);
            o.z = f2bf(olds[cb + cc + 2][i] * rd);
            o.w = f2bf(olds[cb + cc + 3][i] * rd);
            *(ushort4*)&yb[rowbase + cb + cc] = o;
        }
    }
}

extern "C" void kernel_launch(void* const* d_in, const int* in_sizes, int n_in,
                              void* d_out, int out_size, void* d_ws, size_t ws_size,
                              hipStream_t stream) {
    (void)in_sizes; (void)n_in; (void)out_size; (void)ws_size;
    const float* hs = (const float*)d_in[0];
    const float* Wq = (const float*)d_in[1];
    const float* Wk = (const float*)d_in[2];
    const float* Wv = (const float*)d_in[3];
    const float* Wo = (const float*)d_in[4];
    float* out = (float*)d_out;

    // bf16 workspace (~51.5 MB)
    unsigned short* hsb = (unsigned short*)d_ws;        // [BT][HID]
    unsigned short* wqk = hsb + (size_t)BT * HID;       // [384][HID]  (Wq ; Wk)
    unsigned short* wvb = wqk + (size_t)384 * HID;      // [HID][HID]
    unsigned short* wob = wvb + (size_t)HID * HID;      // [HID][HID]
    unsigned short* qkb = wob + (size_t)HID * HID;      // [BT][384]
    unsigned short* vtg = qkb + (size_t)BT * 384;       // [HID][BT]  (V^T)
    unsigned short* ybb = vtg + (size_t)HID * BT;       // [BT][HID]

    dim3 blk(256);
    cvt_all<<<dim3(5664), blk, 0, stream>>>(hs, Wq, Wk, Wv, Wo, hsb, wqk, wvb, wob);

    // fused Q/K projection + V^T projection
    proj_qkv<<<dim3(480), blk, 0, stream>>>(hsb, wqk, wvb, qkb, vtg);

    based_attn_mfma<<<dim3(T / 64 * NH * B), blk, 0, stream>>>(qkb, vtg, ybb);

    // output projection (fp32 out)
    proj_out<<<dim3(12, 32), blk, 0, stream>>>(ybb, wob, out);
}

// Round 3
// 218.389 us; speedup vs baseline: 1.7471x; 1.7471x over previous
//
#include <hip/hip_runtime.h>

#define B 2
#define T 2048
#define HID 1536
#define NH 12
#define DK 16
#define DV 128
#define BT (B * T)
#define EPS 1e-12f

typedef __attribute__((ext_vector_type(8))) short bf16x8;
typedef __attribute__((ext_vector_type(4))) float f32x4;

__device__ __forceinline__ unsigned short f2bf(float f) {
    unsigned int u = __float_as_uint(f);
    u += 0x7FFFu + ((u >> 16) & 1u);
    return (unsigned short)(u >> 16);
}

// ---------------------------------------------------------------------------
// Fused fp32->bf16 for all 5 inputs. Segments in 2048-element blocks:
// hs 3072 | Wq 144 | Wk 144 | Wv 1152 | Wo 1152 = 5664 blocks.
// Wq+Wk land concatenated in wqk [384][1536].
// ---------------------------------------------------------------------------
__global__ __launch_bounds__(256) void cvt_all(const float* __restrict__ hs,
                                               const float* __restrict__ Wq,
                                               const float* __restrict__ Wk,
                                               const float* __restrict__ Wv,
                                               const float* __restrict__ Wo,
                                               unsigned short* __restrict__ hsb,
                                               unsigned short* __restrict__ wqk,
                                               unsigned short* __restrict__ wvb,
                                               unsigned short* __restrict__ wob) {
    int bx = blockIdx.x;
    const float* src;
    unsigned short* dst;
    if (bx < 3072)      { src = hs; dst = hsb; }
    else if (bx < 3216) { src = Wq; dst = wqk;          bx -= 3072; }
    else if (bx < 3360) { src = Wk; dst = wqk + 294912; bx -= 3216; }
    else if (bx < 4512) { src = Wv; dst = wvb;          bx -= 3360; }
    else                { src = Wo; dst = wob;          bx -= 4512; }
    const int i = (bx * 256 + threadIdx.x) * 8;
    float4 a = *(const float4*)(src + i);
    float4 b = *(const float4*)(src + i + 4);
    *(ushort4*)(dst + i)     = make_ushort4(f2bf(a.x), f2bf(a.y), f2bf(a.z), f2bf(a.w));
    *(ushort4*)(dst + i + 4) = make_ushort4(f2bf(b.x), f2bf(b.y), f2bf(b.z), f2bf(b.w));
}

// ---------------------------------------------------------------------------
// 128x64 bf16 GEMM tile body (BK=32, global_load_lds w=16, 16x16x32 MFMA,
// 4 waves x 4x2 frags; per-wave 64x32 output). Smaller tile than 128x128 so
// the small GEMMs in this problem get 2x the blocks -> ~3-4 waves/SIMD
// (grid-limited occupancy was the bottleneck at 128x128: 480/384 blocks on
// 256 CUs = 1.5-1.9 blocks/CU). C bf16 row-major, no store guards.
// ---------------------------------------------------------------------------
__device__ __forceinline__ void gemm_tile_bf16(const unsigned short* __restrict__ A,
                                               const unsigned short* __restrict__ Bm,
                                               unsigned short* __restrict__ C,
                                               int m0, int n0, int K, int ldc,
                                               unsigned short* As, unsigned short* Bs) {
    const int tid = threadIdx.x;
    const int wave = tid >> 6, lane = tid & 63;
    const int wm = (wave & 1) * 64, wn = (wave >> 1) * 32;
    const int fr = lane & 15;
    const int fk = (lane >> 4) * 8;

    f32x4 acc[4][2];
#pragma unroll
    for (int i = 0; i < 4; ++i)
#pragma unroll
        for (int j = 0; j < 2; ++j) acc[i][j] = (f32x4)0.f;

    const int c0 = tid, c1 = tid + 256;
    const int r0 = c0 >> 2, q0 = (c0 & 3) * 8;   // r0 in [0,64)
    const int r1 = c1 >> 2, q1 = (c1 & 3) * 8;   // r1 in [64,128)

    for (int k0 = 0; k0 < K; k0 += 32) {
        // A tile: 128 rows x 32 cols = 512 16B-chunks -> 2 per thread
        __builtin_amdgcn_global_load_lds(
            (const __attribute__((address_space(1))) void*)(A + (size_t)(m0 + r0) * K + k0 + q0),
            (__attribute__((address_space(3))) void*)(As + c0 * 8), 16, 0, 0);
        __builtin_amdgcn_global_load_lds(
            (const __attribute__((address_space(1))) void*)(A + (size_t)(m0 + r1) * K + k0 + q1),
            (__attribute__((address_space(3))) void*)(As + c1 * 8), 16, 0, 0);
        // B tile: 64 rows x 32 cols = 256 chunks -> 1 per thread
        __builtin_amdgcn_global_load_lds(
            (const __attribute__((address_space(1))) void*)(Bm + (size_t)(n0 + r0) * K + k0 + q0),
            (__attribute__((address_space(3))) void*)(Bs + c0 * 8), 16, 0, 0);
        __syncthreads();

        bf16x8 af[4], bfr[2];
#pragma unroll
        for (int mb = 0; mb < 4; ++mb)
            af[mb] = *(const bf16x8*)(As + (wm + mb * 16 + fr) * 32 + fk);
#pragma unroll
        for (int nb = 0; nb < 2; ++nb)
            bfr[nb] = *(const bf16x8*)(Bs + (wn + nb * 16 + fr) * 32 + fk);
#pragma unroll
        for (int mb = 0; mb < 4; ++mb)
#pragma unroll
            for (int nb = 0; nb < 2; ++nb)
                acc[mb][nb] = __builtin_amdgcn_mfma_f32_16x16x32_bf16(
                    af[mb], bfr[nb], acc[mb][nb], 0, 0, 0);
        __syncthreads();
    }

    const int orow = (lane >> 4) * 4;
#pragma unroll
    for (int nb = 0; nb < 2; ++nb) {
        const int col = n0 + wn + nb * 16 + fr;
#pragma unroll
        for (int mb = 0; mb < 4; ++mb) {
            const int row = m0 + wm + mb * 16 + orow;
#pragma unroll
            for (int r = 0; r < 4; ++r)
                C[(size_t)(row + r) * ldc + col] = f2bf(acc[mb][nb][r]);
        }
    }
}

// ---------------------------------------------------------------------------
// Fused QK-proj + V^T-proj, one launch, 960 blocks (128x64 tiles):
//   bx <  192: qk[BT][384] = hsb @ wqk^T          (m-tile bx/6, n-tile bx%6)
//   bx >= 192: vt[HID][BT] = wvb @ hsb^T (V^T)    (4-wide n-supertile swizzle)
// ---------------------------------------------------------------------------
__global__ __launch_bounds__(256) void proj_qkv(const unsigned short* __restrict__ hsb,
                                                const unsigned short* __restrict__ wqk,
                                                const unsigned short* __restrict__ wvb,
                                                unsigned short* __restrict__ qkb,
                                                unsigned short* __restrict__ vtg) {
    __shared__ unsigned short As[128 * 32];
    __shared__ unsigned short Bs[64 * 32];
    const int bx = blockIdx.x;
    if (bx < 192) {
        gemm_tile_bf16(hsb, wqk, qkb, (bx / 6) * 128, (bx % 6) * 64, HID, 384, As, Bs);
    } else {
        const int vid = bx - 192;                 // [0,768)
        const int grp = vid / 48, sub = vid % 48; // grp in [0,16)
        const int n_t = grp * 4 + (sub & 3);      // [0,64)
        const int m_t = sub >> 2;                 // [0,12)
        gemm_tile_bf16(wvb, hsb, vtg, m_t * 128, n_t * 64, HID, BT, As, Bs);
    }
}

// ---------------------------------------------------------------------------
// Output projection: out[BT][HID] fp32 = ybb @ wob^T. 128x64 tiles, 768 blocks.
// ---------------------------------------------------------------------------
__global__ __launch_bounds__(256) void proj_out(const unsigned short* __restrict__ A,
                                                const unsigned short* __restrict__ Bm,
                                                float* __restrict__ C) {
    __shared__ unsigned short As[128 * 32];
    __shared__ unsigned short Bs[64 * 32];
    const int tid = threadIdx.x;
    const int m0 = blockIdx.y * 128;
    const int n0 = blockIdx.x * 64;
    const int wave = tid >> 6, lane = tid & 63;
    const int wm = (wave & 1) * 64, wn = (wave >> 1) * 32;
    const int fr = lane & 15;
    const int fk = (lane >> 4) * 8;
    const int K = HID;

    f32x4 acc[4][2];
#pragma unroll
    for (int i = 0; i < 4; ++i)
#pragma unroll
        for (int j = 0; j < 2; ++j) acc[i][j] = (f32x4)0.f;

    const int c0 = tid, c1 = tid + 256;
    const int r0 = c0 >> 2, q0 = (c0 & 3) * 8;
    const int r1 = c1 >> 2, q1 = (c1 & 3) * 8;

    for (int k0 = 0; k0 < K; k0 += 32) {
        __builtin_amdgcn_global_load_lds(
            (const __attribute__((address_space(1))) void*)(A + (size_t)(m0 + r0) * K + k0 + q0),
            (__attribute__((address_space(3))) void*)(As + c0 * 8), 16, 0, 0);
        __builtin_amdgcn_global_load_lds(
            (const __attribute__((address_space(1))) void*)(A + (size_t)(m0 + r1) * K + k0 + q1),
            (__attribute__((address_space(3))) void*)(As + c1 * 8), 16, 0, 0);
        __builtin_amdgcn_global_load_lds(
            (const __attribute__((address_space(1))) void*)(Bm + (size_t)(n0 + r0) * K + k0 + q0),
            (__attribute__((address_space(3))) void*)(Bs + c0 * 8), 16, 0, 0);
        __syncthreads();

        bf16x8 af[4], bfr[2];
#pragma unroll
        for (int mb = 0; mb < 4; ++mb)
            af[mb] = *(const bf16x8*)(As + (wm + mb * 16 + fr) * 32 + fk);
#pragma unroll
        for (int nb = 0; nb < 2; ++nb)
            bfr[nb] = *(const bf16x8*)(Bs + (wn + nb * 16 + fr) * 32 + fk);
#pragma unroll
        for (int mb = 0; mb < 4; ++mb)
#pragma unroll
            for (int nb = 0; nb < 2; ++nb)
                acc[mb][nb] = __builtin_amdgcn_mfma_f32_16x16x32_bf16(
                    af[mb], bfr[nb], acc[mb][nb], 0, 0, 0);
        __syncthreads();
    }

    const int orow = (lane >> 4) * 4;
#pragma unroll
    for (int nb = 0; nb < 2; ++nb) {
        const int col = n0 + wn + nb * 16 + fr;
#pragma unroll
        for (int mb = 0; mb < 4; ++mb) {
            const int row = m0 + wm + mb * 16 + orow;
#pragma unroll
            for (int r = 0; r < 4; ++r)
                C[(size_t)(row + r) * HID + col] = acc[mb][nb][r];
        }
    }
}

// ---------------------------------------------------------------------------
// MFMA causal Taylor linear attention, software-pipelined (round-0 version).
//   S^T = K Q^T ; S = 1 + a/4 + a^2/32, causal mask on diag tile only
//   O^T = V^T S^T ; y = O^T/den
// Pipelining: kt+1's K/V^T fragments are issued before tile kt's compute, so
// their ~250-cyc latency overlaps S-MFMA + poly + barrier + O-MFMA.
// K-frag load is de-predicated (clamped column): upper-quad k>=16 garbage is
// annihilated by the zeroed Q B-frag. S stored to LDS via trunc bit-pack.
// 768 blocks, qt-major heavy-first.
// ---------------------------------------------------------------------------
__global__ __launch_bounds__(256) void based_attn_mfma(const unsigned short* __restrict__ qk,
                                                       const unsigned short* __restrict__ vt,
                                                       unsigned short* __restrict__ yb) {
    const int bx = blockIdx.x;
    const int qt = (T / 64 - 1) - (bx / (NH * B));
    const int hb = bx % (NH * B);
    const int h  = hb >> 1;
    const int bi = hb & 1;
    const int tid = threadIdx.x;
    const int wave = tid >> 6, lane = tid & 63;
    const int fr = lane & 15, quad = lane >> 4;
    const int fk = quad * 8;
    const int fkk = (quad & 1) * 8;   // clamped column for K A-frag (in-bounds)

    __shared__ __attribute__((aligned(16))) unsigned short ss[2][64][72];
    __shared__ float den_lds[64];
    if (tid < 64) den_lds[tid] = 0.f;

    const bf16x8 zf = {};
    // persistent Q B-frags: B[k][n] = Q[n=i][k], i = nt*16+fr; k>=16 zeroed
    bf16x8 qf[4];
#pragma unroll
    for (int nt = 0; nt < 4; ++nt) {
        qf[nt] = zf;
        if (quad < 2)
            qf[nt] = *(const bf16x8*)&qk[(size_t)(bi * T + qt * 64 + nt * 16 + fr) * 384
                                         + h * DK + fk];
    }

    f32x4 oacc[2][4];
#pragma unroll
    for (int mt = 0; mt < 2; ++mt)
#pragma unroll
        for (int nt = 0; nt < 4; ++nt) oacc[mt][nt] = (f32x4)0.f;
    float denp[4] = {0.f, 0.f, 0.f, 0.f};

    // base pointers (row 0 of this block's slice)
    const unsigned short* kbase = qk + (size_t)(bi * T + wave * 16 + fr) * 384 + 192 + h * DK + fkk;
    const unsigned short* vbase0 = vt + (size_t)(h * DV + wave * 32 + fr) * BT + bi * T + fk;
    const unsigned short* vbase1 = vbase0 + (size_t)16 * BT;

    // prologue: prefetch kt=0
    bf16x8 kf_n = *(const bf16x8*)kbase;
    bf16x8 vf_n[2][2];
    vf_n[0][0] = *(const bf16x8*)(vbase0);
    vf_n[0][1] = *(const bf16x8*)(vbase0 + 32);
    vf_n[1][0] = *(const bf16x8*)(vbase1);
    vf_n[1][1] = *(const bf16x8*)(vbase1 + 32);

    for (int kt = 0; kt <= qt; ++kt) {
        const int bsel = kt & 1;
        const bf16x8 kf = kf_n;
        bf16x8 vf[2][2];
        vf[0][0] = vf_n[0][0]; vf[0][1] = vf_n[0][1];
        vf[1][0] = vf_n[1][0]; vf[1][1] = vf_n[1][1];

        // prefetch kt+1 (clamped on last iteration; redundant but in-bounds)
        {
            const int ktn = (kt < qt) ? kt + 1 : qt;
            kf_n = *(const bf16x8*)(kbase + (size_t)ktn * 64 * 384);
            const int off = ktn * 64;
            vf_n[0][0] = *(const bf16x8*)(vbase0 + off);
            vf_n[0][1] = *(const bf16x8*)(vbase0 + off + 32);
            vf_n[1][0] = *(const bf16x8*)(vbase1 + off);
            vf_n[1][1] = *(const bf16x8*)(vbase1 + off + 32);
        }

        // S^T: wave owns j-strip [wave*16, wave*16+16)
        f32x4 sa[4];
#pragma unroll
        for (int nt = 0; nt < 4; ++nt)
            sa[nt] = __builtin_amdgcn_mfma_f32_16x16x32_bf16(kf, qf[nt], (f32x4)0.f, 0, 0, 0);

#pragma unroll
        for (int nt = 0; nt < 4; ++nt) {
            const int i = nt * 16 + fr;
            float sv[4];
#pragma unroll
            for (int r = 0; r < 4; ++r) {
                const float a = sa[nt][r];
                sv[r] = fmaf(a, fmaf(a, 1.f / 32.f, 0.25f), 1.f);
            }
            if (kt == qt) {   // wave-uniform: causal mask only on diag tile
#pragma unroll
                for (int r = 0; r < 4; ++r) {
                    const int j = wave * 16 + quad * 4 + r;
                    if (j > i) sv[r] = 0.f;
                }
            }
            denp[nt] += sv[0] + sv[1] + sv[2] + sv[3];
            uint2 pk;
            pk.x = (__float_as_uint(sv[0]) >> 16) | (__float_as_uint(sv[1]) & 0xFFFF0000u);
            pk.y = (__float_as_uint(sv[2]) >> 16) | (__float_as_uint(sv[3]) & 0xFFFF0000u);
            *(uint2*)&ss[bsel][i][wave * 16 + quad * 4] = pk;
        }
        __syncthreads();

        // O^T += V^T S^T : wave owns c-chunk [wave*32, wave*32+32)
#pragma unroll
        for (int k2 = 0; k2 < 2; ++k2) {
            bf16x8 sf[4];
#pragma unroll
            for (int nt = 0; nt < 4; ++nt)
                sf[nt] = *(const bf16x8*)&ss[bsel][nt * 16 + fr][k2 * 32 + fk];
#pragma unroll
            for (int mt = 0; mt < 2; ++mt)
#pragma unroll
                for (int nt = 0; nt < 4; ++nt)
                    oacc[mt][nt] = __builtin_amdgcn_mfma_f32_16x16x32_bf16(
                        vf[mt][k2], sf[nt], oacc[mt][nt], 0, 0, 0);
        }
    }

    // den: quad-reduce (same fr), then cross-wave via LDS atomics
#pragma unroll
    for (int nt = 0; nt < 4; ++nt) {
        float v = denp[nt];
        v += __shfl_xor(v, 16);
        v += __shfl_xor(v, 32);
        if (quad == 0) atomicAdd(&den_lds[nt * 16 + fr], v);
    }
    __syncthreads();

    // y[i][c] = O^T[c][i] / den[i], bf16 row-major [BT][HID]
#pragma unroll
    for (int nt = 0; nt < 4; ++nt) {
        const int i = nt * 16 + fr;
        const float rd = 1.f / (den_lds[i] + EPS);
        const size_t rowbase = (size_t)(bi * T + qt * 64 + i) * (NH * DV) + h * DV;
#pragma unroll
        for (int mt = 0; mt < 2; ++mt) {
            const int c = wave * 32 + mt * 16 + quad * 4;
            const f32x4 o = oacc[mt][nt];
            *(ushort4*)&yb[rowbase + c] = make_ushort4(f2bf(o[0] * rd), f2bf(o[1] * rd),
                                                       f2bf(o[2] * rd), f2bf(o[3] * rd));
        }
    }
}

extern "C" void kernel_launch(void* const* d_in, const int* in_sizes, int n_in,
                              void* d_out, int out_size, void* d_ws, size_t ws_size,
                              hipStream_t stream) {
    (void)in_sizes; (void)n_in; (void)out_size; (void)ws_size;
    const float* hs = (const float*)d_in[0];
    const float* Wq = (const float*)d_in[1];
    const float* Wk = (const float*)d_in[2];
    const float* Wv = (const float*)d_in[3];
    const float* Wo = (const float*)d_in[4];
    float* out = (float*)d_out;

    // bf16 workspace (~51.5 MB)
    unsigned short* hsb = (unsigned short*)d_ws;        // [BT][HID]
    unsigned short* wqk = hsb + (size_t)BT * HID;       // [384][HID]  (Wq ; Wk)
    unsigned short* wvb = wqk + (size_t)384 * HID;      // [HID][HID]
    unsigned short* wob = wvb + (size_t)HID * HID;      // [HID][HID]
    unsigned short* qkb = wob + (size_t)HID * HID;      // [BT][384]
    unsigned short* vtg = qkb + (size_t)BT * 384;       // [HID][BT]  (V^T)
    unsigned short* ybb = vtg + (size_t)HID * BT;       // [BT][HID]

    dim3 blk(256);
    cvt_all<<<dim3(5664), blk, 0, stream>>>(hs, Wq, Wk, Wv, Wo, hsb, wqk, wvb, wob);

    // fused Q/K projection + V^T projection (128x64 tiles, 960 blocks)
    proj_qkv<<<dim3(960), blk, 0, stream>>>(hsb, wqk, wvb, qkb, vtg);

    based_attn_mfma<<<dim3(T / 64 * NH * B), blk, 0, stream>>>(qkb, vtg, ybb);

    // output projection (fp32 out, 128x64 tiles, 768 blocks)
    proj_out<<<dim3(24, 32), blk, 0, stream>>>(ybb, wob, out);
}

// Round 4
// 215.278 us; speedup vs baseline: 1.7724x; 1.0144x over previous
//
#include <hip/hip_runtime.h>

#define B 2
#define T 2048
#define HID 1536
#define NH 12
#define DK 16
#define DV 128
#define BT (B * T)
#define EPS 1e-12f

typedef __attribute__((ext_vector_type(8))) short bf16x8;
typedef __attribute__((ext_vector_type(4))) float f32x4;

__device__ __forceinline__ unsigned short f2bf(float f) {
    unsigned int u = __float_as_uint(f);
    u += 0x7FFFu + ((u >> 16) & 1u);
    return (unsigned short)(u >> 16);
}

// ---------------------------------------------------------------------------
// Fused fp32->bf16 for all 5 inputs. Segments in 2048-element blocks:
// hs 3072 | Wq 144 | Wk 144 | Wv 1152 | Wo 1152 = 5664 blocks.
// Wq+Wk land concatenated in wqk [384][1536].
// ---------------------------------------------------------------------------
__global__ __launch_bounds__(256) void cvt_all(const float* __restrict__ hs,
                                               const float* __restrict__ Wq,
                                               const float* __restrict__ Wk,
                                               const float* __restrict__ Wv,
                                               const float* __restrict__ Wo,
                                               unsigned short* __restrict__ hsb,
                                               unsigned short* __restrict__ wqk,
                                               unsigned short* __restrict__ wvb,
                                               unsigned short* __restrict__ wob) {
    int bx = blockIdx.x;
    const float* src;
    unsigned short* dst;
    if (bx < 3072)      { src = hs; dst = hsb; }
    else if (bx < 3216) { src = Wq; dst = wqk;          bx -= 3072; }
    else if (bx < 3360) { src = Wk; dst = wqk + 294912; bx -= 3216; }
    else if (bx < 4512) { src = Wv; dst = wvb;          bx -= 3360; }
    else                { src = Wo; dst = wob;          bx -= 4512; }
    const int i = (bx * 256 + threadIdx.x) * 8;
    float4 a = *(const float4*)(src + i);
    float4 b = *(const float4*)(src + i + 4);
    *(ushort4*)(dst + i)     = make_ushort4(f2bf(a.x), f2bf(a.y), f2bf(a.z), f2bf(a.w));
    *(ushort4*)(dst + i + 4) = make_ushort4(f2bf(b.x), f2bf(b.y), f2bf(b.z), f2bf(b.w));
}

// ---------------------------------------------------------------------------
// Generic m97-style 128x128 bf16 GEMM tile body (BK=32, global_load_lds w=16,
// 16x16x32 MFMA, 4 waves x 4x4 frags). C bf16 row-major, no store guards
// (M,N multiples of 128). [Round-0 version — 128x64 regressed, reverted.]
// ---------------------------------------------------------------------------
__device__ __forceinline__ void gemm_tile_bf16(const unsigned short* __restrict__ A,
                                               const unsigned short* __restrict__ Bm,
                                               unsigned short* __restrict__ C,
                                               int m0, int n0, int K, int ldc,
                                               unsigned short* As, unsigned short* Bs) {
    const int tid = threadIdx.x;
    const int wave = tid >> 6, lane = tid & 63;
    const int wm = (wave & 1) * 64, wn = (wave >> 1) * 64;
    const int fr = lane & 15;
    const int fk = (lane >> 4) * 8;

    f32x4 acc[4][4];
#pragma unroll
    for (int i = 0; i < 4; ++i)
#pragma unroll
        for (int j = 0; j < 4; ++j) acc[i][j] = (f32x4)0.f;

    const int c0 = tid, c1 = tid + 256;
    const int r0 = c0 >> 2, q0 = (c0 & 3) * 8;
    const int r1 = c1 >> 2, q1 = (c1 & 3) * 8;

    for (int k0 = 0; k0 < K; k0 += 32) {
        __builtin_amdgcn_global_load_lds(
            (const __attribute__((address_space(1))) void*)(A + (size_t)(m0 + r0) * K + k0 + q0),
            (__attribute__((address_space(3))) void*)(As + c0 * 8), 16, 0, 0);
        __builtin_amdgcn_global_load_lds(
            (const __attribute__((address_space(1))) void*)(A + (size_t)(m0 + r1) * K + k0 + q1),
            (__attribute__((address_space(3))) void*)(As + c1 * 8), 16, 0, 0);
        __builtin_amdgcn_global_load_lds(
            (const __attribute__((address_space(1))) void*)(Bm + (size_t)(n0 + r0) * K + k0 + q0),
            (__attribute__((address_space(3))) void*)(Bs + c0 * 8), 16, 0, 0);
        __builtin_amdgcn_global_load_lds(
            (const __attribute__((address_space(1))) void*)(Bm + (size_t)(n0 + r1) * K + k0 + q1),
            (__attribute__((address_space(3))) void*)(Bs + c1 * 8), 16, 0, 0);
        __syncthreads();

        bf16x8 af[4], bfr[4];
#pragma unroll
        for (int mb = 0; mb < 4; ++mb)
            af[mb] = *(const bf16x8*)(As + (wm + mb * 16 + fr) * 32 + fk);
#pragma unroll
        for (int nb = 0; nb < 4; ++nb)
            bfr[nb] = *(const bf16x8*)(Bs + (wn + nb * 16 + fr) * 32 + fk);
#pragma unroll
        for (int mb = 0; mb < 4; ++mb)
#pragma unroll
            for (int nb = 0; nb < 4; ++nb)
                acc[mb][nb] = __builtin_amdgcn_mfma_f32_16x16x32_bf16(
                    af[mb], bfr[nb], acc[mb][nb], 0, 0, 0);
        __syncthreads();
    }

    const int orow = (lane >> 4) * 4;
#pragma unroll
    for (int nb = 0; nb < 4; ++nb) {
        const int col = n0 + wn + nb * 16 + fr;
#pragma unroll
        for (int mb = 0; mb < 4; ++mb) {
            const int row = m0 + wm + mb * 16 + orow;
#pragma unroll
            for (int r = 0; r < 4; ++r)
                C[(size_t)(row + r) * ldc + col] = f2bf(acc[mb][nb][r]);
        }
    }
}

// ---------------------------------------------------------------------------
// Fused QK-proj + V^T-proj, one launch, 480 blocks (round-0 version):
//   bx <  96: qk[BT][384] = hsb @ wqk^T           (m-tile bx/3, n-tile bx%3)
//   bx >= 96: vt[HID][BT] = wvb @ hsb^T (V^T)      (4-wide n-supertile swizzle)
// ---------------------------------------------------------------------------
__global__ __launch_bounds__(256) void proj_qkv(const unsigned short* __restrict__ hsb,
                                                const unsigned short* __restrict__ wqk,
                                                const unsigned short* __restrict__ wvb,
                                                unsigned short* __restrict__ qkb,
                                                unsigned short* __restrict__ vtg) {
    __shared__ unsigned short As[128 * 32];
    __shared__ unsigned short Bs[128 * 32];
    const int bx = blockIdx.x;
    if (bx < 96) {
        gemm_tile_bf16(hsb, wqk, qkb, (bx / 3) * 128, (bx % 3) * 128, HID, 384, As, Bs);
    } else {
        const int vid = bx - 96;
        const int grp = vid / 48, sub = vid % 48;
        const int n_t = grp * 4 + (sub & 3), m_t = sub >> 2;
        gemm_tile_bf16(wvb, hsb, vtg, m_t * 128, n_t * 128, HID, BT, As, Bs);
    }
}

// ---------------------------------------------------------------------------
// Output projection: out[BT][HID] fp32 = ybb @ wob^T. (round-0 version)
// ---------------------------------------------------------------------------
__global__ __launch_bounds__(256) void proj_out(const unsigned short* __restrict__ A,
                                                const unsigned short* __restrict__ Bm,
                                                float* __restrict__ C) {
    __shared__ unsigned short As[128 * 32];
    __shared__ unsigned short Bs[128 * 32];
    const int tid = threadIdx.x;
    const int m0 = blockIdx.y * 128;
    const int n0 = blockIdx.x * 128;
    const int wave = tid >> 6, lane = tid & 63;
    const int wm = (wave & 1) * 64, wn = (wave >> 1) * 64;
    const int fr = lane & 15;
    const int fk = (lane >> 4) * 8;
    const int K = HID;

    f32x4 acc[4][4];
#pragma unroll
    for (int i = 0; i < 4; ++i)
#pragma unroll
        for (int j = 0; j < 4; ++j) acc[i][j] = (f32x4)0.f;

    const int c0 = tid, c1 = tid + 256;
    const int r0 = c0 >> 2, q0 = (c0 & 3) * 8;
    const int r1 = c1 >> 2, q1 = (c1 & 3) * 8;

    for (int k0 = 0; k0 < K; k0 += 32) {
        __builtin_amdgcn_global_load_lds(
            (const __attribute__((address_space(1))) void*)(A + (size_t)(m0 + r0) * K + k0 + q0),
            (__attribute__((address_space(3))) void*)(As + c0 * 8), 16, 0, 0);
        __builtin_amdgcn_global_load_lds(
            (const __attribute__((address_space(1))) void*)(A + (size_t)(m0 + r1) * K + k0 + q1),
            (__attribute__((address_space(3))) void*)(As + c1 * 8), 16, 0, 0);
        __builtin_amdgcn_global_load_lds(
            (const __attribute__((address_space(1))) void*)(Bm + (size_t)(n0 + r0) * K + k0 + q0),
            (__attribute__((address_space(3))) void*)(Bs + c0 * 8), 16, 0, 0);
        __builtin_amdgcn_global_load_lds(
            (const __attribute__((address_space(1))) void*)(Bm + (size_t)(n0 + r1) * K + k0 + q1),
            (__attribute__((address_space(3))) void*)(Bs + c1 * 8), 16, 0, 0);
        __syncthreads();

        bf16x8 af[4], bfr[4];
#pragma unroll
        for (int mb = 0; mb < 4; ++mb)
            af[mb] = *(const bf16x8*)(As + (wm + mb * 16 + fr) * 32 + fk);
#pragma unroll
        for (int nb = 0; nb < 4; ++nb)
            bfr[nb] = *(const bf16x8*)(Bs + (wn + nb * 16 + fr) * 32 + fk);
#pragma unroll
        for (int mb = 0; mb < 4; ++mb)
#pragma unroll
            for (int nb = 0; nb < 4; ++nb)
                acc[mb][nb] = __builtin_amdgcn_mfma_f32_16x16x32_bf16(
                    af[mb], bfr[nb], acc[mb][nb], 0, 0, 0);
        __syncthreads();
    }

    const int orow = (lane >> 4) * 4;
#pragma unroll
    for (int nb = 0; nb < 4; ++nb) {
        const int col = n0 + wn + nb * 16 + fr;
#pragma unroll
        for (int mb = 0; mb < 4; ++mb) {
            const int row = m0 + wm + mb * 16 + orow;
#pragma unroll
            for (int r = 0; r < 4; ++r)
                C[(size_t)(row + r) * HID + col] = acc[mb][nb][r];
        }
    }
}

// ---------------------------------------------------------------------------
// MFMA causal Taylor linear attention, software-pipelined, DV-SPLIT.
//   Each block handles HALF the V rows (dvh selects rows [dvh*64, dvh*64+64)
//   of V^T for its head) -> 1536 blocks (6/CU resident vs 1.6 avg before).
//   S strip-set (S-MFMA + poly + LDS pack) is duplicated across the 2 dv
//   halves; O-MFMA work halves per block (8/wave instead of 16).
//   S^T = K Q^T ; S = 1 + a/4 + a^2/32, causal mask on diag tile only
//   O^T = V^T S^T ; y = O^T/den.  qt-major heavy-first.
// ---------------------------------------------------------------------------
__global__ __launch_bounds__(256) void based_attn_mfma(const unsigned short* __restrict__ qk,
                                                       const unsigned short* __restrict__ vt,
                                                       unsigned short* __restrict__ yb) {
    const int bx = blockIdx.x;
    const int qt = (T / 64 - 1) - (bx / (NH * B * 2));
    const int rem = bx % (NH * B * 2);
    const int h   = rem >> 2;
    const int dvh = (rem >> 1) & 1;
    const int bi  = rem & 1;
    const int tid = threadIdx.x;
    const int wave = tid >> 6, lane = tid & 63;
    const int fr = lane & 15, quad = lane >> 4;
    const int fk = quad * 8;
    const int fkk = (quad & 1) * 8;   // clamped column for K A-frag (in-bounds)

    __shared__ __attribute__((aligned(16))) unsigned short ss[2][64][72];
    __shared__ float den_lds[64];
    if (tid < 64) den_lds[tid] = 0.f;

    const bf16x8 zf = {};
    // persistent Q B-frags: B[k][n] = Q[n=i][k], i = nt*16+fr; k>=16 zeroed
    bf16x8 qf[4];
#pragma unroll
    for (int nt = 0; nt < 4; ++nt) {
        qf[nt] = zf;
        if (quad < 2)
            qf[nt] = *(const bf16x8*)&qk[(size_t)(bi * T + qt * 64 + nt * 16 + fr) * 384
                                         + h * DK + fk];
    }

    f32x4 oacc[4];
#pragma unroll
    for (int nt = 0; nt < 4; ++nt) oacc[nt] = (f32x4)0.f;
    float denp[4] = {0.f, 0.f, 0.f, 0.f};

    // base pointers (row 0 of this block's slice)
    const unsigned short* kbase = qk + (size_t)(bi * T + wave * 16 + fr) * 384 + 192 + h * DK + fkk;
    // V^T rows for this block: h*DV + dvh*64 + wave*16 + fr
    const unsigned short* vbase = vt + (size_t)(h * DV + dvh * 64 + wave * 16 + fr) * BT
                                  + bi * T + fk;

    // prologue: prefetch kt=0
    bf16x8 kf_n = *(const bf16x8*)kbase;
    bf16x8 vf_n[2];
    vf_n[0] = *(const bf16x8*)(vbase);
    vf_n[1] = *(const bf16x8*)(vbase + 32);

    for (int kt = 0; kt <= qt; ++kt) {
        const int bsel = kt & 1;
        const bf16x8 kf = kf_n;
        bf16x8 vf[2];
        vf[0] = vf_n[0]; vf[1] = vf_n[1];

        // prefetch kt+1 (clamped on last iteration; redundant but in-bounds)
        {
            const int ktn = (kt < qt) ? kt + 1 : qt;
            kf_n = *(const bf16x8*)(kbase + (size_t)ktn * 64 * 384);
            const int off = ktn * 64;
            vf_n[0] = *(const bf16x8*)(vbase + off);
            vf_n[1] = *(const bf16x8*)(vbase + off + 32);
        }

        // S^T: wave owns j-strip [wave*16, wave*16+16)
        f32x4 sa[4];
#pragma unroll
        for (int nt = 0; nt < 4; ++nt)
            sa[nt] = __builtin_amdgcn_mfma_f32_16x16x32_bf16(kf, qf[nt], (f32x4)0.f, 0, 0, 0);

#pragma unroll
        for (int nt = 0; nt < 4; ++nt) {
            const int i = nt * 16 + fr;
            float sv[4];
#pragma unroll
            for (int r = 0; r < 4; ++r) {
                const float a = sa[nt][r];
                sv[r] = fmaf(a, fmaf(a, 1.f / 32.f, 0.25f), 1.f);
            }
            if (kt == qt) {   // wave-uniform: causal mask only on diag tile
#pragma unroll
                for (int r = 0; r < 4; ++r) {
                    const int j = wave * 16 + quad * 4 + r;
                    if (j > i) sv[r] = 0.f;
                }
            }
            denp[nt] += sv[0] + sv[1] + sv[2] + sv[3];
            uint2 pk;
            pk.x = (__float_as_uint(sv[0]) >> 16) | (__float_as_uint(sv[1]) & 0xFFFF0000u);
            pk.y = (__float_as_uint(sv[2]) >> 16) | (__float_as_uint(sv[3]) & 0xFFFF0000u);
            *(uint2*)&ss[bsel][i][wave * 16 + quad * 4] = pk;
        }
        __syncthreads();

        // O^T += V^T S^T : wave owns c-chunk [wave*16, wave*16+16) of this half
#pragma unroll
        for (int k2 = 0; k2 < 2; ++k2) {
            bf16x8 sf[4];
#pragma unroll
            for (int nt = 0; nt < 4; ++nt)
                sf[nt] = *(const bf16x8*)&ss[bsel][nt * 16 + fr][k2 * 32 + fk];
#pragma unroll
            for (int nt = 0; nt < 4; ++nt)
                oacc[nt] = __builtin_amdgcn_mfma_f32_16x16x32_bf16(
                    vf[k2], sf[nt], oacc[nt], 0, 0, 0);
        }
    }

    // den: quad-reduce (same fr), then cross-wave via LDS atomics
#pragma unroll
    for (int nt = 0; nt < 4; ++nt) {
        float v = denp[nt];
        v += __shfl_xor(v, 16);
        v += __shfl_xor(v, 32);
        if (quad == 0) atomicAdd(&den_lds[nt * 16 + fr], v);
    }
    __syncthreads();

    // y[i][c] = O^T[c][i] / den[i], bf16 row-major [BT][HID]; this block's
    // columns are h*DV + dvh*64 + [wave*16+quad*4 .. +4)
#pragma unroll
    for (int nt = 0; nt < 4; ++nt) {
        const int i = nt * 16 + fr;
        const float rd = 1.f / (den_lds[i] + EPS);
        const size_t rowbase = (size_t)(bi * T + qt * 64 + i) * (NH * DV) + h * DV + dvh * 64;
        const int c = wave * 16 + quad * 4;
        const f32x4 o = oacc[nt];
        *(ushort4*)&yb[rowbase + c] = make_ushort4(f2bf(o[0] * rd), f2bf(o[1] * rd),
                                                   f2bf(o[2] * rd), f2bf(o[3] * rd));
    }
}

extern "C" void kernel_launch(void* const* d_in, const int* in_sizes, int n_in,
                              void* d_out, int out_size, void* d_ws, size_t ws_size,
                              hipStream_t stream) {
    (void)in_sizes; (void)n_in; (void)out_size; (void)ws_size;
    const float* hs = (const float*)d_in[0];
    const float* Wq = (const float*)d_in[1];
    const float* Wk = (const float*)d_in[2];
    const float* Wv = (const float*)d_in[3];
    const float* Wo = (const float*)d_in[4];
    float* out = (float*)d_out;

    // bf16 workspace (~51.5 MB)
    unsigned short* hsb = (unsigned short*)d_ws;        // [BT][HID]
    unsigned short* wqk = hsb + (size_t)BT * HID;       // [384][HID]  (Wq ; Wk)
    unsigned short* wvb = wqk + (size_t)384 * HID;      // [HID][HID]
    unsigned short* wob = wvb + (size_t)HID * HID;      // [HID][HID]
    unsigned short* qkb = wob + (size_t)HID * HID;      // [BT][384]
    unsigned short* vtg = qkb + (size_t)BT * 384;       // [HID][BT]  (V^T)
    unsigned short* ybb = vtg + (size_t)HID * BT;       // [BT][HID]

    dim3 blk(256);
    cvt_all<<<dim3(5664), blk, 0, stream>>>(hs, Wq, Wk, Wv, Wo, hsb, wqk, wvb, wob);

    // fused Q/K projection + V^T projection (128x128 tiles, 480 blocks)
    proj_qkv<<<dim3(480), blk, 0, stream>>>(hsb, wqk, wvb, qkb, vtg);

    // DV-split attention: 1536 blocks
    based_attn_mfma<<<dim3(T / 64 * NH * B * 2), blk, 0, stream>>>(qkb, vtg, ybb);

    // output projection (fp32 out, 128x128 tiles)
    proj_out<<<dim3(12, 32), blk, 0, stream>>>(ybb, wob, out);
}